// Round 14
// baseline (6651.062 us; speedup 1.0000x reference)
//
#include <hip/hip_runtime.h>
#include <hip/hip_bf16.h>
#include <cstdint>

#define T_STEPS 512
#define BATCH   64
#define XDIM    64
#define HDIM    1024
#define YDIM    64
#define BH      (BATCH * HDIM)
#define RING_D  32

// per-block weight slice in LDS: 4 combos x (16KB rz + 8KB n) = 96KB
#define WBLK_BYTES   98304
#define COMBO_BYTES  24576
#define TL1_OFF      16384
#define LDS_TOTAL    131072   // 96KB weights + 32KB exchange (validated budget)

typedef unsigned short ushort_t;
typedef uint32_t u32;
typedef unsigned long long u64;
typedef __attribute__((ext_vector_type(8))) short short8;
typedef __attribute__((ext_vector_type(4))) float f32x4;

union U4S8 { uint4 u; short8 s; };

// ---------- helpers ----------
__device__ __forceinline__ u32 f2bf_u(float x) {
  u32 u = __float_as_uint(x);
  return (u + 0x7fffu + ((u >> 16) & 1u)) >> 16;  // round-nearest-even
}
__device__ __forceinline__ ushort_t f2bf(float x) { return (ushort_t)f2bf_u(x); }

__device__ __forceinline__ float sigm(float x) { return 1.0f / (1.0f + expf(-x)); }

// ---------- coherence-point (sc1) helpers ----------
__device__ __forceinline__ void st_sc32(u32* p, u32 v) {
  __hip_atomic_store(p, v, __ATOMIC_RELAXED, __HIP_MEMORY_SCOPE_AGENT);
}
// plain cached 16B load, issue-ordered
__device__ __forceinline__ uint4 ld_g128(const ushort_t* p) {
  uint4 r;
  asm volatile("global_load_dwordx4 %0, %1, off" : "=v"(r) : "v"(p));
  return r;
}
// one 16B sc1 flag read + drain; returns all-4 >= tag
__device__ __forceinline__ int flags_ok(const u32* p, u32 tag) {
  uint4 f;
  asm volatile("global_load_dwordx4 %0, %1, off sc1\n\ts_waitcnt vmcnt(0)"
               : "=v"(f) : "v"(p) : "memory");
  return (f.x >= tag) && (f.y >= tag) && (f.z >= tag) && (f.w >= tag);
}
// thread t (0..31) guards flags[4t..4t+3]
__device__ __forceinline__ void poll4(const u32* flags, int t, u32 tag) {
  const u32* p = flags + 4 * t;
  while (!flags_ok(p, tag)) __builtin_amdgcn_s_sleep(1);
}

// ---------- encoder ----------
__global__ __launch_bounds__(256) void enc_kernel(
    const float* __restrict__ x, const float* __restrict__ enc_w,
    const float* __restrict__ enc_b, ushort_t* __restrict__ enc_out)
{
  __shared__ float wlds[64 * 65];
  const int lane = threadIdx.x & 63;
  const int wv   = threadIdx.x >> 6;
  const int cb = blockIdx.x & 15;
  const int rb = blockIdx.x >> 4;
  const int j  = cb * 64 + lane;
  const int r0 = rb * 16 + wv * 4;

  const float* wsrc = enc_w + (size_t)cb * 64 * XDIM;
  for (int i = threadIdx.x; i < 4096; i += 256)
    wlds[(i >> 6) * 65 + (i & 63)] = wsrc[i];
  __syncthreads();

  const float* xr = x + (size_t)r0 * XDIM;
  float acc[4] = {0.f, 0.f, 0.f, 0.f};
#pragma unroll
  for (int k = 0; k < XDIM; k += 4) {
    const float w0 = wlds[lane * 65 + k];
    const float w1 = wlds[lane * 65 + k + 1];
    const float w2 = wlds[lane * 65 + k + 2];
    const float w3 = wlds[lane * 65 + k + 3];
#pragma unroll
    for (int rr = 0; rr < 4; ++rr) {
      const float* xp = xr + rr * XDIM + k;
      acc[rr] = fmaf(xp[3], w3, fmaf(xp[2], w2, fmaf(xp[1], w1, fmaf(xp[0], w0, acc[rr]))));
    }
  }
  const float b = enc_b[j];
#pragma unroll
  for (int rr = 0; rr < 4; ++rr)
    enc_out[(size_t)(r0 + rr) * HDIM + j] = f2bf(tanhf(acc[rr] + b));
}

// ---------- GRU weight pre-pack (identical to validated round-10 layout) ----------
__global__ __launch_bounds__(256) void wprep_kernel(
    const float* __restrict__ w_ih, const float* __restrict__ w_hh,
    ushort_t* __restrict__ wfrag)
{
  const int lane = threadIdx.x & 63;
  const int wv   = threadIdx.x >> 6;
  const int c    = blockIdx.x * 4 + wv;
  const int ko = c & 15;
  const int tl = (c >> 4) & 1;
  const int c2 = (c >> 5) & 3;
  const int bid = c >> 7;
  const int g = c2 >> 1, kh = c2 & 1;
  const int layer = bid >> 7;
  const int j0 = (bid & 127) * 8;
  const float* wsrc = (g ? w_hh : w_ih) + (size_t)layer * 3 * HDIM * HDIM;

  if (tl == 0) {
    const int col = lane & 15, kgrp = lane >> 4;
    const int k = kh * 512 + ko * 32 + kgrp * 8;
    const int row = (col < 8) ? (j0 + col) : (HDIM + j0 + col - 8);
    const float* src = wsrc + (size_t)row * HDIM + k;
    short8 v;
#pragma unroll
    for (int e = 0; e < 8; ++e) v[e] = (short)f2bf(src[e]);
    const size_t byte = (size_t)bid * WBLK_BYTES + c2 * COMBO_BYTES + ko * 1024 + lane * 16;
    *(short8*)((char*)wfrag + byte) = v;
  } else if (lane < 32) {
    const int kgrp = lane >> 3, col = lane & 7;
    const int k = kh * 512 + ko * 32 + kgrp * 8;
    const int row = 2 * HDIM + j0 + col;
    const float* src = wsrc + (size_t)row * HDIM + k;
    short8 v;
#pragma unroll
    for (int e = 0; e < 8; ++e) v[e] = (short)f2bf(src[e]);
    const size_t byte = (size_t)bid * WBLK_BYTES + c2 * COMBO_BYTES + TL1_OFF + ko * 512 + lane * 16;
    *(short8*)((char*)wfrag + byte) = v;
  }
}

// ---------- dec/head weight frag pre-pack ----------
__global__ __launch_bounds__(256) void wprep2_kernel(
    const float* __restrict__ dec_w, const float* __restrict__ exp_w,
    const float* __restrict__ log_w,
    ushort_t* __restrict__ dwfrag, ushort_t* __restrict__ hwfrag)
{
  const int lane = threadIdx.x & 63;
  const int wv   = threadIdx.x >> 6;
  const int c    = blockIdx.x * 4 + wv;   // 0..2303
  short8 v;
  if (c < 2048) {
    const int nt = c >> 5, kc = c & 31;
    const int row = nt * 16 + (lane & 15);
    const int k   = kc * 32 + (lane >> 4) * 8;
    const float* src = dec_w + (size_t)row * HDIM + k;
#pragma unroll
    for (int e = 0; e < 8; ++e) v[e] = (short)f2bf(src[e]);
    *(short8*)(dwfrag + (size_t)c * 512 + lane * 8) = v;
  } else {
    const int c2 = c - 2048;
    const int nt = c2 >> 5, kc = c2 & 31;
    const int row = nt * 16 + (lane & 15);
    const int k   = kc * 32 + (lane >> 4) * 8;
    const float* src = (row < 64) ? (exp_w + (size_t)row * HDIM + k)
                                  : (log_w + (size_t)(row - 64) * HDIM + k);
#pragma unroll
    for (int e = 0; e < 8; ++e) v[e] = (short)f2bf(src[e]);
    *(short8*)(hwfrag + (size_t)c2 * 512 + lane * 8) = v;
  }
}

// ---------- persistent recurrent kernel ----------
// 256 blocks x 1024 threads (16 waves). L0 = blocks 0..127; L1 = 128..255.
// Wave wid: mq = wid&3 (16-row block), g = (wid>>2)&1 (ih/hh), kh = wid>>3 (K-half).
// Per wave: 16 loads + 32 MFMAs; publishes 2 tiles. 4 waves/SIMD.
__global__ __launch_bounds__(1024, 1) void rnn_persist(
    const ushort_t* __restrict__ ench1,
    const ushort_t* __restrict__ wfrag,
    const float* __restrict__ b_ih, const float* __restrict__ b_hh,
    ushort_t* __restrict__ h0ring,        // 32 x [64][1024] bf16
    ushort_t* __restrict__ h1ring,        // 32 x [64][1024] bf16
    ushort_t* __restrict__ h1_all,        // == ench1 (slices for dechead)
    u32* __restrict__ l0_flags, u32* __restrict__ l1_flags)
{
  extern __shared__ char smem[];          // 96K weights + 32K exchange
  float* lds_part = (float*)(smem + WBLK_BYTES);   // 32 tiles x 256 f32

  const int tid  = threadIdx.x;
  const int lane = tid & 63;
  const int wid  = tid >> 6;              // 0..15
  const int bid  = blockIdx.x;
  const int layer = bid >> 7;
  const int j0    = (bid & 127) * 8;
  const int mq = wid & 3, g = (wid >> 2) & 1, kh = wid >> 3;
  const int col = lane & 15, kgrp = lane >> 4;
  const bool isL1 = (layer == 1);
  const int gbid = bid & 127;
  u32* ownf = isL1 ? l1_flags : l0_flags;

  // ---- one-time: stage 96KB weight image into LDS ----
  {
    const uint4* src = (const uint4*)((const char*)wfrag + (size_t)bid * WBLK_BYTES);
    uint4* dst = (uint4*)smem;
#pragma unroll 2
    for (int i = tid; i < WBLK_BYTES / 16; i += 1024) dst[i] = src[i];
  }

  // per-wave LDS weight addresses (full K-half combo, same as round 10)
  const int c2 = g * 2 + kh;
  const char* w0 = smem + c2 * COMBO_BYTES + lane * 16;                               // +ko*1024
  const char* w1 = smem + c2 * COMBO_BYTES + TL1_OFF + (kgrp * 8 + (col & 7)) * 16;   // +ko*512

  // ---- biases ----
  float bA = 0.f, bB = 0.f, bC = 0.f;
  {
    const float* bi = b_ih + layer * 3 * HDIM;
    const float* bh = b_hh + layer * 3 * HDIM;
    if (col < 8) {
      const int j = j0 + col;
      bA = bi[j] + bh[j];
      bB = bi[2 * HDIM + j];
      bC = bh[2 * HDIM + j];
    } else {
      const int j = j0 + col - 8;
      bA = bi[HDIM + j] + bh[HDIM + j];
    }
  }

  f32x4 hp = {0.f, 0.f, 0.f, 0.f};  // running fp32 h-state (waves 0-3, col<8)

  __syncthreads();  // LDS weight image ready

  for (int i = 0; i < T_STEPS; ++i) {
    // ---- P1: L1 waits for h0(i) ----
    if (isL1) {
      if (tid < 32) poll4(l0_flags, tid, (u32)(i + 1));
      __syncthreads();
    }

    const ushort_t* A1 = isL1 ? (h0ring + (size_t)(i & (RING_D - 1)) * BH)
                              : (ench1 + (size_t)i * BH);
    const ushort_t* A2 = isL1 ? (h1ring + (size_t)((i - 1) & (RING_D - 1)) * BH)
                              : (h0ring + (size_t)((i - 1) & (RING_D - 1)) * BH);
    const ushort_t* A = g ? A2 : A1;
    const ushort_t* Arow = A + (size_t)(mq * 16 + col) * HDIM + kh * 512 + kgrp * 8;

    // ---- A loads for g=0 waves (dependency already satisfied): overlap with P2 poll ----
    uint4 areg[16];
    if (g == 0) {
#pragma unroll
      for (int ko = 0; ko < 16; ++ko) areg[ko] = ld_g128(Arow + ko * 32);
    }

    // ---- P2: own-group barrier (h(i-1) ready) + L0 ring guard ----
    if (tid < 32) {
      poll4(ownf, tid, (u32)i);
      if (!isL1 && i >= RING_D) poll4(l1_flags, tid, (u32)(i - RING_D + 1));
    }
    __syncthreads();

    // ---- A loads for g=1 waves ----
    if (g == 1) {
#pragma unroll
      for (int ko = 0; ko < 16; ++ko) areg[ko] = ld_g128(Arow + ko * 32);
    }

    // ---- MFMA, staged waits ----
    f32x4 acc0 = {0,0,0,0}, acc1 = {0,0,0,0};
    asm volatile("s_waitcnt vmcnt(8)" ::: "memory");
    __builtin_amdgcn_sched_barrier(0);
#pragma unroll
    for (int ko = 0; ko < 8; ++ko) {
      const short8 b0 = *(const short8*)(w0 + ko * 1024);
      const short8 b1 = *(const short8*)(w1 + ko * 512);
      U4S8 a; a.u = areg[ko];
      acc0 = __builtin_amdgcn_mfma_f32_16x16x32_bf16(a.s, b0, acc0, 0, 0, 0);
      acc1 = __builtin_amdgcn_mfma_f32_16x16x32_bf16(a.s, b1, acc1, 0, 0, 0);
    }
    asm volatile("s_waitcnt vmcnt(0)" ::: "memory");
    __builtin_amdgcn_sched_barrier(0);
#pragma unroll
    for (int ko = 8; ko < 16; ++ko) {
      const short8 b0 = *(const short8*)(w0 + ko * 1024);
      const short8 b1 = *(const short8*)(w1 + ko * 512);
      U4S8 a; a.u = areg[ko];
      acc0 = __builtin_amdgcn_mfma_f32_16x16x32_bf16(a.s, b0, acc0, 0, 0, 0);
      acc1 = __builtin_amdgcn_mfma_f32_16x16x32_bf16(a.s, b1, acc1, 0, 0, 0);
    }

    // publish 2 tiles: idx = wid*2 + tl
    const int base = (wid * 2) * 256 + lane * 4;
    *(f32x4*)&lds_part[base      ] = acc0;
    *(f32x4*)&lds_part[base + 256] = acc1;

    __syncthreads();  // all 32 tiles visible

    if (wid < 4) {
      const int m = wid;               // batch rows m*16 .. +15
      const int lo = lane * 4;
      // producer wave (kh, g, m) = kh*8 + g*4 + m; tile = wave*2 + tl
      const int t_ih0 = (0 * 8 + 0 * 4 + m) * 2;
      const int t_hh0 = (0 * 8 + 1 * 4 + m) * 2;
      const int t_ih1 = (1 * 8 + 0 * 4 + m) * 2;
      const int t_hh1 = (1 * 8 + 1 * 4 + m) * 2;
      f32x4 girz = *(f32x4*)&lds_part[t_ih0 * 256 + lo] + *(f32x4*)&lds_part[t_ih1 * 256 + lo];
      f32x4 gin  = *(f32x4*)&lds_part[(t_ih0 + 1) * 256 + lo] + *(f32x4*)&lds_part[(t_ih1 + 1) * 256 + lo];
      f32x4 ghrz = *(f32x4*)&lds_part[t_hh0 * 256 + lo] + *(f32x4*)&lds_part[t_hh1 * 256 + lo];
      f32x4 ghn  = *(f32x4*)&lds_part[(t_hh0 + 1) * 256 + lo] + *(f32x4*)&lds_part[(t_hh1 + 1) * 256 + lo];

      ushort_t* hdst = isL1 ? (h1ring + (size_t)(i & (RING_D - 1)) * BH)
                            : (h0ring + (size_t)(i & (RING_D - 1)) * BH);
      ushort_t* hall = isL1 ? (h1_all + (size_t)i * BH) : (ushort_t*)0;

#pragma unroll
      for (int e = 0; e < 4; ++e) {
        const float rz = sigm(girz[e] + ghrz[e] + bA);
        const float nv = tanhf(gin[e] + bB + rz * (ghn[e] + bC));
        const float zv = __shfl_xor(rz, 8);
        const int b = m * 16 + kgrp * 4 + e;
        float h = 0.f;
        if (col < 8) {
          h = (1.f - zv) * nv + zv * hp[e];
          hp[e] = h;
        }
        const u32 hb = f2bf_u(h);
        const u32 pb = (u32)__shfl_xor((int)hb, 1);
        if (col < 8 && (col & 1) == 0) {
          const u32 pack = hb | (pb << 16);
          st_sc32((u32*)(hdst + b * HDIM + j0 + col), pack);
          if (hall) st_sc32((u32*)(hall + b * HDIM + j0 + col), pack);
        }
      }
    }

    __syncthreads();  // all waves' stores drained (vmcnt 0) before flag arrival
    if (tid == 0) st_sc32(ownf + gbid, (u32)(i + 1));
  }
}

// ---------- fused decoder + heads (bf16 MFMA) ----------
#define AST 1032
__global__ __launch_bounds__(512, 1) void dechead_kernel(
    const ushort_t* __restrict__ h1_all,
    const ushort_t* __restrict__ dwfrag, const ushort_t* __restrict__ hwfrag,
    const float* __restrict__ dec_b, const float* __restrict__ exp_b,
    const float* __restrict__ log_b, float* __restrict__ out)
{
  extern __shared__ char smem2[];
  ushort_t* Alds = (ushort_t*)smem2;             // [32][AST]
  ushort_t* Rlds = Alds + 32 * AST;              // [32][AST]

  const int tid  = threadIdx.x;
  const int lane = tid & 63;
  const int wv   = tid >> 6;
  const int base = blockIdx.x * 32;

  {
    const uint4* src = (const uint4*)(h1_all + (size_t)base * HDIM);
#pragma unroll
    for (int ii = 0; ii < 8; ++ii) {
      const int idx = ii * 512 + tid;
      const int row = idx >> 7;
      const int k   = (idx & 127) * 8;
      *(uint4*)(Alds + row * AST + k) = src[idx];
    }
  }
  __syncthreads();

  f32x4 acc[8][2];
#pragma unroll
  for (int t = 0; t < 8; ++t) { acc[t][0] = (f32x4){0,0,0,0}; acc[t][1] = (f32x4){0,0,0,0}; }

  const int r0 = lane & 15, kg = lane >> 4;
  const int nt0 = wv * 8;
#pragma unroll 1
  for (int t = 0; t < 8; ++t) {
    const ushort_t* bsrc = dwfrag + (size_t)(nt0 + t) * 32 * 512 + lane * 8;
    f32x4 c0 = acc[t][0], c1 = acc[t][1];
#pragma unroll
    for (int kc = 0; kc < 32; ++kc) {
      const short8 b  = *(const short8*)(bsrc + kc * 512);
      const short8 a0 = *(const short8*)(Alds + r0 * AST + kc * 32 + kg * 8);
      const short8 a1 = *(const short8*)(Alds + (16 + r0) * AST + kc * 32 + kg * 8);
      c0 = __builtin_amdgcn_mfma_f32_16x16x32_bf16(a0, b, c0, 0, 0, 0);
      c1 = __builtin_amdgcn_mfma_f32_16x16x32_bf16(a1, b, c1, 0, 0, 0);
    }
    acc[t][0] = c0; acc[t][1] = c1;
  }

#pragma unroll
  for (int t = 0; t < 8; ++t) {
    const int colc = (nt0 + t) * 16 + r0;
    const float db = dec_b[colc];
#pragma unroll
    for (int m = 0; m < 2; ++m) {
      const f32x4 v = acc[t][m];
#pragma unroll
      for (int e = 0; e < 4; ++e) {
        const int row = m * 16 + kg * 4 + e;
        Rlds[row * AST + colc] = (ushort_t)f2bf_u(tanhf(v[e] + db));
      }
    }
  }
  __syncthreads();

  f32x4 h0a = {0,0,0,0}, h1a = {0,0,0,0};
  {
    const ushort_t* bsrc = hwfrag + (size_t)wv * 32 * 512 + lane * 8;
#pragma unroll
    for (int kc = 0; kc < 32; ++kc) {
      const short8 b  = *(const short8*)(bsrc + kc * 512);
      const short8 a0 = *(const short8*)(Rlds + r0 * AST + kc * 32 + kg * 8);
      const short8 a1 = *(const short8*)(Rlds + (16 + r0) * AST + kc * 32 + kg * 8);
      h0a = __builtin_amdgcn_mfma_f32_16x16x32_bf16(a0, b, h0a, 0, 0, 0);
      h1a = __builtin_amdgcn_mfma_f32_16x16x32_bf16(a1, b, h1a, 0, 0, 0);
    }
  }
  const int y = wv * 16 + r0;
  if (wv < 4) {
    const float eb = exp_b[y];
#pragma unroll
    for (int m = 0; m < 2; ++m) {
      const f32x4 v = (m == 0) ? h0a : h1a;
#pragma unroll
      for (int e = 0; e < 4; ++e) {
        const int row = m * 16 + kg * 4 + e;
        out[(size_t)(base + row) * YDIM + y] = v[e] + eb;
      }
    }
  } else {
    const int yv = y - 64;
    const float lb = log_b[yv];
#pragma unroll
    for (int m = 0; m < 2; ++m) {
      const f32x4 v = (m == 0) ? h0a : h1a;
#pragma unroll
      for (int e = 0; e < 4; ++e) {
        const int row = m * 16 + kg * 4 + e;
        out[(size_t)(T_STEPS * BATCH * YDIM) + (size_t)(base + row) * YDIM + yv] = expf(v[e] + lb);
      }
    }
  }
}

// ---------- host ----------
extern "C" void kernel_launch(void* const* d_in, const int* in_sizes, int n_in,
                              void* d_out, int out_size, void* d_ws, size_t ws_size,
                              hipStream_t stream) {
  (void)in_sizes; (void)n_in; (void)out_size; (void)ws_size;
  const float* x     = (const float*)d_in[0];
  const float* enc_w = (const float*)d_in[1];
  const float* enc_b = (const float*)d_in[2];
  const float* w_ih  = (const float*)d_in[3];
  const float* w_hh  = (const float*)d_in[4];
  const float* b_ih  = (const float*)d_in[5];
  const float* b_hh  = (const float*)d_in[6];
  const float* dec_w = (const float*)d_in[7];
  const float* dec_b = (const float*)d_in[8];
  const float* exp_w = (const float*)d_in[9];
  const float* exp_b = (const float*)d_in[10];
  const float* log_w = (const float*)d_in[11];
  const float* log_b = (const float*)d_in[12];
  float* out = (float*)d_out;

  char* ws = (char*)d_ws;
  u32*      l0f     = (u32*)ws;                             // 128 u32 (contiguous)
  u32*      l1f     = (u32*)(ws + 4096);                    // 128 u32
  ushort_t* wfrag   = (ushort_t*)(ws + 2097152);            // 24 MB
  ushort_t* h0ring  = (ushort_t*)(ws + 27262976);           // 4 MB (32 slots)
  ushort_t* h1ring  = (ushort_t*)(ws + 31457280);           // 4 MB
  ushort_t* ench1   = (ushort_t*)(ws + 35651584);           // 64 MB enc slices / h1_all
  ushort_t* dwfrag  = (ushort_t*)(ws + 102760448);          // 2 MB
  ushort_t* hwfrag  = (ushort_t*)(ws + 104857600);          // 256 KB

  hipMemsetAsync(ws, 0, 8192, stream);                      // flag arrays
  hipMemsetAsync(ws + 27262976, 0, 8388608, stream);        // both rings

  enc_kernel<<<32768, 256, 0, stream>>>(x, enc_w, enc_b, ench1);
  wprep_kernel<<<8192, 256, 0, stream>>>(w_ih, w_hh, wfrag);
  wprep2_kernel<<<576, 256, 0, stream>>>(dec_w, exp_w, log_w, dwfrag, hwfrag);

  {
    (void)hipFuncSetAttribute((const void*)rnn_persist,
                        hipFuncAttributeMaxDynamicSharedMemorySize, LDS_TOTAL);
    (void)hipFuncSetAttribute((const void*)dechead_kernel,
                        hipFuncAttributeMaxDynamicSharedMemorySize, 2 * 32 * AST * 2);
    void* args[9];
    args[0] = (void*)&ench1;
    args[1] = (void*)&wfrag;
    args[2] = (void*)&b_ih;
    args[3] = (void*)&b_hh;
    args[4] = (void*)&h0ring;
    args[5] = (void*)&h1ring;
    args[6] = (void*)&ench1;
    args[7] = (void*)&l0f;
    args[8] = (void*)&l1f;
    hipError_t cerr = hipLaunchCooperativeKernel((const void*)rnn_persist,
                                                 dim3(256), dim3(1024),
                                                 args, LDS_TOTAL, stream);
    if (cerr != hipSuccess) {
      // fallback: plain launch (grid == CU count, 1 block/CU -> co-resident)
      rnn_persist<<<256, 1024, LDS_TOTAL, stream>>>(
          ench1, wfrag, b_ih, b_hh, h0ring, h1ring, ench1, l0f, l1f);
    }
  }

  dechead_kernel<<<1024, 512, 2 * 32 * AST * 2, stream>>>(
      ench1, dwfrag, hwfrag, dec_b, exp_b, log_b, out);
}

// Round 15
// 5850.747 us; speedup vs baseline: 1.1368x; 1.1368x over previous
//
#include <hip/hip_runtime.h>
#include <hip/hip_bf16.h>
#include <cstdint>

#define T_STEPS 512
#define BATCH   64
#define XDIM    64
#define HDIM    1024
#define YDIM    64
#define BH      (BATCH * HDIM)
#define RING_D  32

// per-block weight slice in LDS: 4 combos x (16KB rz + 8KB n) = 96KB
#define WBLK_BYTES   98304
#define COMBO_BYTES  24576
#define TL1_OFF      16384
#define LDS_TOTAL    131072   // 96KB weights + 32KB exchange (validated budget)

typedef unsigned short ushort_t;
typedef uint32_t u32;
typedef unsigned long long u64;
typedef __attribute__((ext_vector_type(8))) short short8;
typedef __attribute__((ext_vector_type(4))) float f32x4;

union U4S8 { uint4 u; short8 s; };

// ---------- helpers ----------
__device__ __forceinline__ u32 f2bf_u(float x) {
  u32 u = __float_as_uint(x);
  return (u + 0x7fffu + ((u >> 16) & 1u)) >> 16;  // round-nearest-even
}
__device__ __forceinline__ ushort_t f2bf(float x) { return (ushort_t)f2bf_u(x); }

__device__ __forceinline__ float sigm(float x) { return 1.0f / (1.0f + expf(-x)); }

// ---------- coherence-point (sc1) helpers ----------
__device__ __forceinline__ void st_sc32(u32* p, u32 v) {
  __hip_atomic_store(p, v, __ATOMIC_RELAXED, __HIP_MEMORY_SCOPE_AGENT);
}
// plain cached 16B load, issue-ordered (asm volatile)
__device__ __forceinline__ uint4 ld_g128(const ushort_t* p) {
  uint4 r;
  asm volatile("global_load_dwordx4 %0, %1, off" : "=v"(r) : "v"(p));
  return r;
}
// one 16B sc1 flag read + drain; returns all-4 >= tag
__device__ __forceinline__ int flags_ok(const u32* p, u32 tag) {
  uint4 f;
  asm volatile("global_load_dwordx4 %0, %1, off sc1\n\ts_waitcnt vmcnt(0)"
               : "=v"(f) : "v"(p) : "memory");
  return (f.x >= tag) && (f.y >= tag) && (f.z >= tag) && (f.w >= tag);
}
// thread t guards flags[4t..4t+3]
__device__ __forceinline__ void poll4(const u32* flags, int t, u32 tag) {
  const u32* p = flags + 4 * t;
  while (!flags_ok(p, tag)) __builtin_amdgcn_s_sleep(1);
}

// ---------- encoder ----------
__global__ __launch_bounds__(256) void enc_kernel(
    const float* __restrict__ x, const float* __restrict__ enc_w,
    const float* __restrict__ enc_b, ushort_t* __restrict__ enc_out)
{
  __shared__ float wlds[64 * 65];
  const int lane = threadIdx.x & 63;
  const int wv   = threadIdx.x >> 6;
  const int cb = blockIdx.x & 15;
  const int rb = blockIdx.x >> 4;
  const int j  = cb * 64 + lane;
  const int r0 = rb * 16 + wv * 4;

  const float* wsrc = enc_w + (size_t)cb * 64 * XDIM;
  for (int i = threadIdx.x; i < 4096; i += 256)
    wlds[(i >> 6) * 65 + (i & 63)] = wsrc[i];
  __syncthreads();

  const float* xr = x + (size_t)r0 * XDIM;
  float acc[4] = {0.f, 0.f, 0.f, 0.f};
#pragma unroll
  for (int k = 0; k < XDIM; k += 4) {
    const float w0 = wlds[lane * 65 + k];
    const float w1 = wlds[lane * 65 + k + 1];
    const float w2 = wlds[lane * 65 + k + 2];
    const float w3 = wlds[lane * 65 + k + 3];
#pragma unroll
    for (int rr = 0; rr < 4; ++rr) {
      const float* xp = xr + rr * XDIM + k;
      acc[rr] = fmaf(xp[3], w3, fmaf(xp[2], w2, fmaf(xp[1], w1, fmaf(xp[0], w0, acc[rr]))));
    }
  }
  const float b = enc_b[j];
#pragma unroll
  for (int rr = 0; rr < 4; ++rr)
    enc_out[(size_t)(r0 + rr) * HDIM + j] = f2bf(tanhf(acc[rr] + b));
}

// ---------- GRU weight pre-pack ----------
__global__ __launch_bounds__(256) void wprep_kernel(
    const float* __restrict__ w_ih, const float* __restrict__ w_hh,
    ushort_t* __restrict__ wfrag)
{
  const int lane = threadIdx.x & 63;
  const int wv   = threadIdx.x >> 6;
  const int c    = blockIdx.x * 4 + wv;
  const int ko = c & 15;
  const int tl = (c >> 4) & 1;
  const int c2 = (c >> 5) & 3;
  const int bid = c >> 7;
  const int g = c2 >> 1, kh = c2 & 1;
  const int layer = bid >> 7;
  const int j0 = (bid & 127) * 8;
  const float* wsrc = (g ? w_hh : w_ih) + (size_t)layer * 3 * HDIM * HDIM;

  if (tl == 0) {
    const int col = lane & 15, kgrp = lane >> 4;
    const int k = kh * 512 + ko * 32 + kgrp * 8;
    const int row = (col < 8) ? (j0 + col) : (HDIM + j0 + col - 8);
    const float* src = wsrc + (size_t)row * HDIM + k;
    short8 v;
#pragma unroll
    for (int e = 0; e < 8; ++e) v[e] = (short)f2bf(src[e]);
    const size_t byte = (size_t)bid * WBLK_BYTES + c2 * COMBO_BYTES + ko * 1024 + lane * 16;
    *(short8*)((char*)wfrag + byte) = v;
  } else if (lane < 32) {
    const int kgrp = lane >> 3, col = lane & 7;
    const int k = kh * 512 + ko * 32 + kgrp * 8;
    const int row = 2 * HDIM + j0 + col;
    const float* src = wsrc + (size_t)row * HDIM + k;
    short8 v;
#pragma unroll
    for (int e = 0; e < 8; ++e) v[e] = (short)f2bf(src[e]);
    const size_t byte = (size_t)bid * WBLK_BYTES + c2 * COMBO_BYTES + TL1_OFF + ko * 512 + lane * 16;
    *(short8*)((char*)wfrag + byte) = v;
  }
}

// ---------- dec/head weight frag pre-pack ----------
__global__ __launch_bounds__(256) void wprep2_kernel(
    const float* __restrict__ dec_w, const float* __restrict__ exp_w,
    const float* __restrict__ log_w,
    ushort_t* __restrict__ dwfrag, ushort_t* __restrict__ hwfrag)
{
  const int lane = threadIdx.x & 63;
  const int wv   = threadIdx.x >> 6;
  const int c    = blockIdx.x * 4 + wv;   // 0..2303
  short8 v;
  if (c < 2048) {
    const int nt = c >> 5, kc = c & 31;
    const int row = nt * 16 + (lane & 15);
    const int k   = kc * 32 + (lane >> 4) * 8;
    const float* src = dec_w + (size_t)row * HDIM + k;
#pragma unroll
    for (int e = 0; e < 8; ++e) v[e] = (short)f2bf(src[e]);
    *(short8*)(dwfrag + (size_t)c * 512 + lane * 8) = v;
  } else {
    const int c2 = c - 2048;
    const int nt = c2 >> 5, kc = c2 & 31;
    const int row = nt * 16 + (lane & 15);
    const int k   = kc * 32 + (lane >> 4) * 8;
    const float* src = (row < 64) ? (exp_w + (size_t)row * HDIM + k)
                                  : (log_w + (size_t)(row - 64) * HDIM + k);
#pragma unroll
    for (int e = 0; e < 8; ++e) v[e] = (short)f2bf(src[e]);
    *(short8*)(hwfrag + (size_t)c2 * 512 + lane * 8) = v;
  }
}

// ---------- persistent recurrent kernel (round-10 base + per-wave flags) ----------
// L0 = blocks 0..127 (producer into 32-deep h0 ring); L1 = blocks 128..255.
// Per-elementwise-wave flags: flags[gbid*4+m], posted after the wave's OWN
// vmcnt(0) drain -- no block barrier / tid-0 hop on the signal path.
// LDS-overwrite safety: every wave passes a __syncthreads (P1/P2) before any
// next-step LDS write, and cannot pass its P2 poll until all 4 elementwise
// waves of the producer step have posted.
__global__ __launch_bounds__(512, 1) void rnn_persist(
    const ushort_t* __restrict__ ench1,
    const ushort_t* __restrict__ wfrag,
    const float* __restrict__ b_ih, const float* __restrict__ b_hh,
    ushort_t* __restrict__ h0ring,        // 32 x [64][1024] bf16
    ushort_t* __restrict__ h1ring,        // 32 x [64][1024] bf16
    ushort_t* __restrict__ h1_all,        // == ench1 (slices for dechead)
    u32* __restrict__ l0_flags, u32* __restrict__ l1_flags)
{
  extern __shared__ char smem[];          // 96K weights + 32K exchange
  float* lds_part = (float*)(smem + WBLK_BYTES);

  const int tid  = threadIdx.x;
  const int lane = tid & 63;
  const int wid  = tid >> 6;
  const int bid  = blockIdx.x;
  const int layer = bid >> 7;
  const int j0    = (bid & 127) * 8;
  const int mp = wid & 1, g = (wid >> 1) & 1, kh = wid >> 2;
  const int col = lane & 15, kgrp = lane >> 4;
  const bool isL1 = (layer == 1);
  const int gbid = bid & 127;
  u32* ownf = isL1 ? l1_flags : l0_flags;

  // ---- one-time: stage 96KB weight image into LDS ----
  {
    const uint4* src = (const uint4*)((const char*)wfrag + (size_t)bid * WBLK_BYTES);
    uint4* dst = (uint4*)smem;
#pragma unroll 4
    for (int i = tid; i < WBLK_BYTES / 16; i += 512) dst[i] = src[i];
  }

  const int c2 = g * 2 + kh;
  const char* w0 = smem + c2 * COMBO_BYTES + lane * 16;
  const char* w1 = smem + c2 * COMBO_BYTES + TL1_OFF + (kgrp * 8 + (col & 7)) * 16;

  // ---- biases ----
  float bA = 0.f, bB = 0.f, bC = 0.f;
  {
    const float* bi = b_ih + layer * 3 * HDIM;
    const float* bh = b_hh + layer * 3 * HDIM;
    if (col < 8) {
      const int j = j0 + col;
      bA = bi[j] + bh[j];
      bB = bi[2 * HDIM + j];
      bC = bh[2 * HDIM + j];
    } else {
      const int j = j0 + col - 8;
      bA = bi[HDIM + j] + bh[HDIM + j];
    }
  }

  f32x4 hp = {0.f, 0.f, 0.f, 0.f};  // running fp32 h-state (waves 0-3, col<8)

  __syncthreads();  // LDS weight image ready

  for (int i = 0; i < T_STEPS; ++i) {
    // ---- P1: L1 waits for h0(i) (512 flags, 4/thread) ----
    if (isL1) {
      if (tid < 128) poll4(l0_flags, tid, (u32)(i + 1));
      __syncthreads();
    }

    const ushort_t* A1 = isL1 ? (h0ring + (size_t)(i & (RING_D - 1)) * BH)
                              : (ench1 + (size_t)i * BH);
    const ushort_t* A2 = isL1 ? (h1ring + (size_t)((i - 1) & (RING_D - 1)) * BH)
                              : (h0ring + (size_t)((i - 1) & (RING_D - 1)) * BH);
    const ushort_t* A = g ? A2 : A1;
    const ushort_t* Arow0 = A + (size_t)(mp * 32 + col) * HDIM + kh * 512 + kgrp * 8;
    const ushort_t* Arow1 = Arow0 + 16 * HDIM;

    // ---- A1 prefetch (g=0 waves): overlaps with own-group poll ----
    uint4 areg[32];
    if (g == 0) {
#pragma unroll
      for (int ko = 0; ko < 16; ++ko) {
        areg[2 * ko]     = ld_g128(Arow0 + ko * 32);
        areg[2 * ko + 1] = ld_g128(Arow1 + ko * 32);
      }
    }

    // ---- P2: own-group barrier (h(i-1) ready) + L0 ring guard ----
    if (tid < 128) {
      poll4(ownf, tid, (u32)i);
      if (!isL1 && i >= RING_D) poll4(l1_flags, tid, (u32)(i - RING_D + 1));
    }
    __syncthreads();

    // ---- A2 loads (g=1 waves) ----
    if (g == 1) {
#pragma unroll
      for (int ko = 0; ko < 16; ++ko) {
        areg[2 * ko]     = ld_g128(Arow0 + ko * 32);
        areg[2 * ko + 1] = ld_g128(Arow1 + ko * 32);
      }
    }

    // ---- MFMA, staged waits ----
    f32x4 acc00 = {0,0,0,0}, acc01 = {0,0,0,0}, acc10 = {0,0,0,0}, acc11 = {0,0,0,0};
    asm volatile("s_waitcnt vmcnt(16)" ::: "memory");
    __builtin_amdgcn_sched_barrier(0);
#pragma unroll
    for (int ko = 0; ko < 8; ++ko) {
      const short8 b0 = *(const short8*)(w0 + ko * 1024);
      const short8 b1 = *(const short8*)(w1 + ko * 512);
      U4S8 a0, a1; a0.u = areg[2 * ko]; a1.u = areg[2 * ko + 1];
      acc00 = __builtin_amdgcn_mfma_f32_16x16x32_bf16(a0.s, b0, acc00, 0, 0, 0);
      acc01 = __builtin_amdgcn_mfma_f32_16x16x32_bf16(a0.s, b1, acc01, 0, 0, 0);
      acc10 = __builtin_amdgcn_mfma_f32_16x16x32_bf16(a1.s, b0, acc10, 0, 0, 0);
      acc11 = __builtin_amdgcn_mfma_f32_16x16x32_bf16(a1.s, b1, acc11, 0, 0, 0);
    }
    asm volatile("s_waitcnt vmcnt(0)" ::: "memory");
    __builtin_amdgcn_sched_barrier(0);
#pragma unroll
    for (int ko = 8; ko < 16; ++ko) {
      const short8 b0 = *(const short8*)(w0 + ko * 1024);
      const short8 b1 = *(const short8*)(w1 + ko * 512);
      U4S8 a0, a1; a0.u = areg[2 * ko]; a1.u = areg[2 * ko + 1];
      acc00 = __builtin_amdgcn_mfma_f32_16x16x32_bf16(a0.s, b0, acc00, 0, 0, 0);
      acc01 = __builtin_amdgcn_mfma_f32_16x16x32_bf16(a0.s, b1, acc01, 0, 0, 0);
      acc10 = __builtin_amdgcn_mfma_f32_16x16x32_bf16(a1.s, b0, acc10, 0, 0, 0);
      acc11 = __builtin_amdgcn_mfma_f32_16x16x32_bf16(a1.s, b1, acc11, 0, 0, 0);
    }

    const int base = (wid * 4) * 256 + lane * 4;
    *(f32x4*)&lds_part[base      ] = acc00;
    *(f32x4*)&lds_part[base + 256] = acc01;
    *(f32x4*)&lds_part[base + 512] = acc10;
    *(f32x4*)&lds_part[base + 768] = acc11;

    __syncthreads();  // all 32 partial tiles visible

    if (wid < 4) {
      const int m = wid, mpe = m >> 1, ime = m & 1;
      const int i00 = ((0 * 4 + 0 * 2 + mpe) * 4 + ime * 2);
      const int i01 = ((1 * 4 + 0 * 2 + mpe) * 4 + ime * 2);
      const int i10 = ((0 * 4 + 1 * 2 + mpe) * 4 + ime * 2);
      const int i11 = ((1 * 4 + 1 * 2 + mpe) * 4 + ime * 2);
      const int lo = lane * 4;
      f32x4 girz = *(f32x4*)&lds_part[i00 * 256 + lo] + *(f32x4*)&lds_part[i01 * 256 + lo];
      f32x4 gin  = *(f32x4*)&lds_part[(i00 + 1) * 256 + lo] + *(f32x4*)&lds_part[(i01 + 1) * 256 + lo];
      f32x4 ghrz = *(f32x4*)&lds_part[i10 * 256 + lo] + *(f32x4*)&lds_part[i11 * 256 + lo];
      f32x4 ghn  = *(f32x4*)&lds_part[(i10 + 1) * 256 + lo] + *(f32x4*)&lds_part[(i11 + 1) * 256 + lo];

      ushort_t* hdst = isL1 ? (h1ring + (size_t)(i & (RING_D - 1)) * BH)
                            : (h0ring + (size_t)(i & (RING_D - 1)) * BH);
      ushort_t* hall = isL1 ? (h1_all + (size_t)i * BH) : (ushort_t*)0;

#pragma unroll
      for (int e = 0; e < 4; ++e) {
        const float rz = sigm(girz[e] + ghrz[e] + bA);
        const float nv = tanhf(gin[e] + bB + rz * (ghn[e] + bC));
        const float zv = __shfl_xor(rz, 8);
        const int b = m * 16 + kgrp * 4 + e;
        float h = 0.f;
        if (col < 8) {
          h = (1.f - zv) * nv + zv * hp[e];
          hp[e] = h;
        }
        const u32 hb = f2bf_u(h);
        const u32 pb = (u32)__shfl_xor((int)hb, 1);
        if (col < 8 && (col & 1) == 0) {
          const u32 pack = hb | (pb << 16);
          st_sc32((u32*)(hdst + b * HDIM + j0 + col), pack);
          if (hall) st_sc32((u32*)(hall + b * HDIM + j0 + col), pack);
        }
      }

      // per-wave completion flag: own stores drained -> post immediately
      asm volatile("s_waitcnt vmcnt(0)" ::: "memory");
      __builtin_amdgcn_sched_barrier(0);
      if (lane == 0) st_sc32(ownf + gbid * 4 + m, (u32)(i + 1));
    }
    // no tail barrier: next-iteration P1/P2 __syncthreads + flag polls guard LDS reuse
  }
}

// ---------- fused decoder + heads (bf16 MFMA) ----------
#define AST 1032
__global__ __launch_bounds__(512, 1) void dechead_kernel(
    const ushort_t* __restrict__ h1_all,
    const ushort_t* __restrict__ dwfrag, const ushort_t* __restrict__ hwfrag,
    const float* __restrict__ dec_b, const float* __restrict__ exp_b,
    const float* __restrict__ log_b, float* __restrict__ out)
{
  extern __shared__ char smem2[];
  ushort_t* Alds = (ushort_t*)smem2;             // [32][AST]
  ushort_t* Rlds = Alds + 32 * AST;              // [32][AST]

  const int tid  = threadIdx.x;
  const int lane = tid & 63;
  const int wv   = tid >> 6;
  const int base = blockIdx.x * 32;

  {
    const uint4* src = (const uint4*)(h1_all + (size_t)base * HDIM);
#pragma unroll
    for (int ii = 0; ii < 8; ++ii) {
      const int idx = ii * 512 + tid;
      const int row = idx >> 7;
      const int k   = (idx & 127) * 8;
      *(uint4*)(Alds + row * AST + k) = src[idx];
    }
  }
  __syncthreads();

  f32x4 acc[8][2];
#pragma unroll
  for (int t = 0; t < 8; ++t) { acc[t][0] = (f32x4){0,0,0,0}; acc[t][1] = (f32x4){0,0,0,0}; }

  const int r0 = lane & 15, kg = lane >> 4;
  const int nt0 = wv * 8;
#pragma unroll 1
  for (int t = 0; t < 8; ++t) {
    const ushort_t* bsrc = dwfrag + (size_t)(nt0 + t) * 32 * 512 + lane * 8;
    f32x4 c0 = acc[t][0], c1 = acc[t][1];
#pragma unroll
    for (int kc = 0; kc < 32; ++kc) {
      const short8 b  = *(const short8*)(bsrc + kc * 512);
      const short8 a0 = *(const short8*)(Alds + r0 * AST + kc * 32 + kg * 8);
      const short8 a1 = *(const short8*)(Alds + (16 + r0) * AST + kc * 32 + kg * 8);
      c0 = __builtin_amdgcn_mfma_f32_16x16x32_bf16(a0, b, c0, 0, 0, 0);
      c1 = __builtin_amdgcn_mfma_f32_16x16x32_bf16(a1, b, c1, 0, 0, 0);
    }
    acc[t][0] = c0; acc[t][1] = c1;
  }

#pragma unroll
  for (int t = 0; t < 8; ++t) {
    const int colc = (nt0 + t) * 16 + r0;
    const float db = dec_b[colc];
#pragma unroll
    for (int m = 0; m < 2; ++m) {
      const f32x4 v = acc[t][m];
#pragma unroll
      for (int e = 0; e < 4; ++e) {
        const int row = m * 16 + kg * 4 + e;
        Rlds[row * AST + colc] = (ushort_t)f2bf_u(tanhf(v[e] + db));
      }
    }
  }
  __syncthreads();

  f32x4 h0a = {0,0,0,0}, h1a = {0,0,0,0};
  {
    const ushort_t* bsrc = hwfrag + (size_t)wv * 32 * 512 + lane * 8;
#pragma unroll
    for (int kc = 0; kc < 32; ++kc) {
      const short8 b  = *(const short8*)(bsrc + kc * 512);
      const short8 a0 = *(const short8*)(Rlds + r0 * AST + kc * 32 + kg * 8);
      const short8 a1 = *(const short8*)(Rlds + (16 + r0) * AST + kc * 32 + kg * 8);
      h0a = __builtin_amdgcn_mfma_f32_16x16x32_bf16(a0, b, h0a, 0, 0, 0);
      h1a = __builtin_amdgcn_mfma_f32_16x16x32_bf16(a1, b, h1a, 0, 0, 0);
    }
  }
  const int y = wv * 16 + r0;
  if (wv < 4) {
    const float eb = exp_b[y];
#pragma unroll
    for (int m = 0; m < 2; ++m) {
      const f32x4 v = (m == 0) ? h0a : h1a;
#pragma unroll
      for (int e = 0; e < 4; ++e) {
        const int row = m * 16 + kg * 4 + e;
        out[(size_t)(base + row) * YDIM + y] = v[e] + eb;
      }
    }
  } else {
    const int yv = y - 64;
    const float lb = log_b[yv];
#pragma unroll
    for (int m = 0; m < 2; ++m) {
      const f32x4 v = (m == 0) ? h0a : h1a;
#pragma unroll
      for (int e = 0; e < 4; ++e) {
        const int row = m * 16 + kg * 4 + e;
        out[(size_t)(T_STEPS * BATCH * YDIM) + (size_t)(base + row) * YDIM + yv] = expf(v[e] + lb);
      }
    }
  }
}

// ---------- host ----------
extern "C" void kernel_launch(void* const* d_in, const int* in_sizes, int n_in,
                              void* d_out, int out_size, void* d_ws, size_t ws_size,
                              hipStream_t stream) {
  (void)in_sizes; (void)n_in; (void)out_size; (void)ws_size;
  const float* x     = (const float*)d_in[0];
  const float* enc_w = (const float*)d_in[1];
  const float* enc_b = (const float*)d_in[2];
  const float* w_ih  = (const float*)d_in[3];
  const float* w_hh  = (const float*)d_in[4];
  const float* b_ih  = (const float*)d_in[5];
  const float* b_hh  = (const float*)d_in[6];
  const float* dec_w = (const float*)d_in[7];
  const float* dec_b = (const float*)d_in[8];
  const float* exp_w = (const float*)d_in[9];
  const float* exp_b = (const float*)d_in[10];
  const float* log_w = (const float*)d_in[11];
  const float* log_b = (const float*)d_in[12];
  float* out = (float*)d_out;

  char* ws = (char*)d_ws;
  u32*      l0f     = (u32*)ws;                             // 512 u32 (contiguous, 2KB)
  u32*      l1f     = (u32*)(ws + 4096);                    // 512 u32
  ushort_t* wfrag   = (ushort_t*)(ws + 2097152);            // 24 MB
  ushort_t* h0ring  = (ushort_t*)(ws + 27262976);           // 4 MB (32 slots)
  ushort_t* h1ring  = (ushort_t*)(ws + 31457280);           // 4 MB
  ushort_t* ench1   = (ushort_t*)(ws + 35651584);           // 64 MB enc slices / h1_all
  ushort_t* dwfrag  = (ushort_t*)(ws + 102760448);          // 2 MB
  ushort_t* hwfrag  = (ushort_t*)(ws + 104857600);          // 256 KB

  hipMemsetAsync(ws, 0, 8192, stream);                      // flag arrays
  hipMemsetAsync(ws + 27262976, 0, 8388608, stream);        // both rings

  enc_kernel<<<32768, 256, 0, stream>>>(x, enc_w, enc_b, ench1);
  wprep_kernel<<<8192, 256, 0, stream>>>(w_ih, w_hh, wfrag);
  wprep2_kernel<<<576, 256, 0, stream>>>(dec_w, exp_w, log_w, dwfrag, hwfrag);

  {
    (void)hipFuncSetAttribute((const void*)rnn_persist,
                        hipFuncAttributeMaxDynamicSharedMemorySize, LDS_TOTAL);
    (void)hipFuncSetAttribute((const void*)dechead_kernel,
                        hipFuncAttributeMaxDynamicSharedMemorySize, 2 * 32 * AST * 2);
    void* args[9];
    args[0] = (void*)&ench1;
    args[1] = (void*)&wfrag;
    args[2] = (void*)&b_ih;
    args[3] = (void*)&b_hh;
    args[4] = (void*)&h0ring;
    args[5] = (void*)&h1ring;
    args[6] = (void*)&ench1;
    args[7] = (void*)&l0f;
    args[8] = (void*)&l1f;
    hipError_t cerr = hipLaunchCooperativeKernel((const void*)rnn_persist,
                                                 dim3(256), dim3(512),
                                                 args, LDS_TOTAL, stream);
    if (cerr != hipSuccess) {
      rnn_persist<<<256, 512, LDS_TOTAL, stream>>>(
          ench1, wfrag, b_ih, b_hh, h0ring, h1ring, ench1, l0f, l1f);
    }
  }

  dechead_kernel<<<1024, 512, 2 * 32 * AST * 2, stream>>>(
      ench1, dwfrag, hwfrag, dec_b, exp_b, log_b, out);
}

// Round 17
// 5584.832 us; speedup vs baseline: 1.1909x; 1.0476x over previous
//
#include <hip/hip_runtime.h>
#include <hip/hip_bf16.h>
#include <cstdint>

#define T_STEPS 512
#define BATCH   64
#define XDIM    64
#define HDIM    1024
#define YDIM    64
#define BH      (BATCH * HDIM)
#define RING_D  32

// per-block weight slice in LDS: 4 combos x (16KB rz + 8KB n) = 96KB
#define WBLK_BYTES   98304
#define COMBO_BYTES  24576
#define TL1_OFF      16384

typedef unsigned short ushort_t;
typedef uint32_t u32;
typedef unsigned long long u64;
typedef __attribute__((ext_vector_type(8))) short short8;
typedef __attribute__((ext_vector_type(4))) float f32x4;

union U4S8 { uint4 u; short8 s; };

// ---------- helpers ----------
__device__ __forceinline__ u32 f2bf_u(float x) {
  u32 u = __float_as_uint(x);
  return (u + 0x7fffu + ((u >> 16) & 1u)) >> 16;  // round-nearest-even
}
__device__ __forceinline__ ushort_t f2bf(float x) { return (ushort_t)f2bf_u(x); }

__device__ __forceinline__ float sigm(float x) { return 1.0f / (1.0f + expf(-x)); }

// ---------- coherence-point (sc1) helpers for flags ----------
__device__ __forceinline__ void st_sc32(u32* p, u32 v) {
  __hip_atomic_store(p, v, __ATOMIC_RELAXED, __HIP_MEMORY_SCOPE_AGENT);
}

// plain cached 16B load, issue-ordered (asm volatile)
__device__ __forceinline__ uint4 ld_g128(const ushort_t* p) {
  uint4 r;
  asm volatile("global_load_dwordx4 %0, %1, off" : "=v"(r) : "v"(p));
  return r;
}

// one 16B sc1 flag read + drain; returns all-4 >= tag
__device__ __forceinline__ int flags_ok(const u32* p, u32 tag) {
  uint4 f;
  asm volatile("global_load_dwordx4 %0, %1, off sc1\n\ts_waitcnt vmcnt(0)"
               : "=v"(f) : "v"(p) : "memory");
  return (f.x >= tag) && (f.y >= tag) && (f.z >= tag) && (f.w >= tag);
}
// thread t (0..31) guards flags[4t..4t+3]
__device__ __forceinline__ void poll4(const u32* flags, int t, u32 tag) {
  const u32* p = flags + 4 * t;
  while (!flags_ok(p, tag)) __builtin_amdgcn_s_sleep(1);
}

// ---------- encoder: LDS-staged weights (coalesced), bf16 out ----------
__global__ __launch_bounds__(256) void enc_kernel(
    const float* __restrict__ x, const float* __restrict__ enc_w,
    const float* __restrict__ enc_b, ushort_t* __restrict__ enc_out)
{
  __shared__ float wlds[64 * 65];
  const int lane = threadIdx.x & 63;
  const int wv   = threadIdx.x >> 6;
  const int cb = blockIdx.x & 15;
  const int rb = blockIdx.x >> 4;
  const int j  = cb * 64 + lane;
  const int r0 = rb * 16 + wv * 4;

  const float* wsrc = enc_w + (size_t)cb * 64 * XDIM;
  for (int i = threadIdx.x; i < 4096; i += 256)
    wlds[(i >> 6) * 65 + (i & 63)] = wsrc[i];
  __syncthreads();

  const float* xr = x + (size_t)r0 * XDIM;
  float acc[4] = {0.f, 0.f, 0.f, 0.f};
#pragma unroll
  for (int k = 0; k < XDIM; k += 4) {
    const float w0 = wlds[lane * 65 + k];
    const float w1 = wlds[lane * 65 + k + 1];
    const float w2 = wlds[lane * 65 + k + 2];
    const float w3 = wlds[lane * 65 + k + 3];
#pragma unroll
    for (int rr = 0; rr < 4; ++rr) {
      const float* xp = xr + rr * XDIM + k;
      acc[rr] = fmaf(xp[3], w3, fmaf(xp[2], w2, fmaf(xp[1], w1, fmaf(xp[0], w0, acc[rr]))));
    }
  }
  const float b = enc_b[j];
#pragma unroll
  for (int rr = 0; rr < 4; ++rr)
    enc_out[(size_t)(r0 + rr) * HDIM + j] = f2bf(tanhf(acc[rr] + b));
}

// ---------- GRU weight pre-pack into per-block LDS image ----------
__global__ __launch_bounds__(256) void wprep_kernel(
    const float* __restrict__ w_ih, const float* __restrict__ w_hh,
    ushort_t* __restrict__ wfrag)
{
  const int lane = threadIdx.x & 63;
  const int wv   = threadIdx.x >> 6;
  const int c    = blockIdx.x * 4 + wv;
  const int ko = c & 15;
  const int tl = (c >> 4) & 1;
  const int c2 = (c >> 5) & 3;
  const int bid = c >> 7;
  const int g = c2 >> 1, kh = c2 & 1;
  const int layer = bid >> 7;
  const int j0 = (bid & 127) * 8;
  const float* wsrc = (g ? w_hh : w_ih) + (size_t)layer * 3 * HDIM * HDIM;

  if (tl == 0) {
    const int col = lane & 15, kgrp = lane >> 4;
    const int k = kh * 512 + ko * 32 + kgrp * 8;
    const int row = (col < 8) ? (j0 + col) : (HDIM + j0 + col - 8);
    const float* src = wsrc + (size_t)row * HDIM + k;
    short8 v;
#pragma unroll
    for (int e = 0; e < 8; ++e) v[e] = (short)f2bf(src[e]);
    const size_t byte = (size_t)bid * WBLK_BYTES + c2 * COMBO_BYTES + ko * 1024 + lane * 16;
    *(short8*)((char*)wfrag + byte) = v;
  } else if (lane < 32) {
    const int kgrp = lane >> 3, col = lane & 7;
    const int k = kh * 512 + ko * 32 + kgrp * 8;
    const int row = 2 * HDIM + j0 + col;
    const float* src = wsrc + (size_t)row * HDIM + k;
    short8 v;
#pragma unroll
    for (int e = 0; e < 8; ++e) v[e] = (short)f2bf(src[e]);
    const size_t byte = (size_t)bid * WBLK_BYTES + c2 * COMBO_BYTES + TL1_OFF + ko * 512 + lane * 16;
    *(short8*)((char*)wfrag + byte) = v;
  }
}

// ---------- dec/head weight frag pre-pack ----------
__global__ __launch_bounds__(256) void wprep2_kernel(
    const float* __restrict__ dec_w, const float* __restrict__ exp_w,
    const float* __restrict__ log_w,
    ushort_t* __restrict__ dwfrag, ushort_t* __restrict__ hwfrag)
{
  const int lane = threadIdx.x & 63;
  const int wv   = threadIdx.x >> 6;
  const int c    = blockIdx.x * 4 + wv;   // 0..2303
  short8 v;
  if (c < 2048) {
    const int nt = c >> 5, kc = c & 31;
    const int row = nt * 16 + (lane & 15);
    const int k   = kc * 32 + (lane >> 4) * 8;
    const float* src = dec_w + (size_t)row * HDIM + k;
#pragma unroll
    for (int e = 0; e < 8; ++e) v[e] = (short)f2bf(src[e]);
    *(short8*)(dwfrag + (size_t)c * 512 + lane * 8) = v;
  } else {
    const int c2 = c - 2048;
    const int nt = c2 >> 5, kc = c2 & 31;
    const int row = nt * 16 + (lane & 15);
    const int k   = kc * 32 + (lane >> 4) * 8;
    const float* src = (row < 64) ? (exp_w + (size_t)row * HDIM + k)
                                  : (log_w + (size_t)(row - 64) * HDIM + k);
#pragma unroll
    for (int e = 0; e < 8; ++e) v[e] = (short)f2bf(src[e]);
    *(short8*)(hwfrag + (size_t)c2 * 512 + lane * 8) = v;
  }
}

// ---------- persistent recurrent kernel ----------
// L0 = blocks 0..127 (producer into 32-deep h0 ring); L1 = blocks 128..255.
// Flattened flag barrier (no leader/release hops); deep-pipelined A prefetch.
__global__ __launch_bounds__(512, 1) void rnn_persist(
    const ushort_t* __restrict__ ench1,
    const ushort_t* __restrict__ wfrag,
    const float* __restrict__ b_ih, const float* __restrict__ b_hh,
    ushort_t* __restrict__ h0ring,        // 32 x [64][1024] bf16
    ushort_t* __restrict__ h1ring,        // 32 x [64][1024] bf16
    ushort_t* __restrict__ h1_all,        // == ench1 (slices for dechead)
    u32* __restrict__ l0_flags, u32* __restrict__ l1_flags)
{
  extern __shared__ char smem[];          // 96KB weights + 32KB exchange
  float* lds_part = (float*)(smem + WBLK_BYTES);

  const int tid  = threadIdx.x;
  const int lane = tid & 63;
  const int wid  = tid >> 6;
  const int bid  = blockIdx.x;
  const int layer = bid >> 7;
  const int j0    = (bid & 127) * 8;
  const int mp = wid & 1, g = (wid >> 1) & 1, kh = wid >> 2;
  const int col = lane & 15, kgrp = lane >> 4;
  const bool isL1 = (layer == 1);
  const int gbid = bid & 127;
  u32* ownf = isL1 ? l1_flags : l0_flags;

  // ---- one-time: stage 96KB weight image into LDS ----
  {
    const uint4* src = (const uint4*)((const char*)wfrag + (size_t)bid * WBLK_BYTES);
    uint4* dst = (uint4*)smem;
#pragma unroll 4
    for (int i = tid; i < WBLK_BYTES / 16; i += 512) dst[i] = src[i];
  }

  const int c2 = g * 2 + kh;
  const char* w0 = smem + c2 * COMBO_BYTES + lane * 16;
  const char* w1 = smem + c2 * COMBO_BYTES + TL1_OFF + (kgrp * 8 + (col & 7)) * 16;

  // ---- biases ----
  float bA = 0.f, bB = 0.f, bC = 0.f;
  {
    const float* bi = b_ih + layer * 3 * HDIM;
    const float* bh = b_hh + layer * 3 * HDIM;
    if (col < 8) {
      const int j = j0 + col;
      bA = bi[j] + bh[j];
      bB = bi[2 * HDIM + j];
      bC = bh[2 * HDIM + j];
    } else {
      const int j = j0 + col - 8;
      bA = bi[HDIM + j] + bh[HDIM + j];
    }
  }

  f32x4 hp = {0.f, 0.f, 0.f, 0.f};  // running fp32 h-state (waves 0-3, col<8)

  __syncthreads();  // LDS weight image ready

  for (int i = 0; i < T_STEPS; ++i) {
    // ---- P1: L1 waits for h0(i) ----
    if (isL1) {
      if (tid < 32) poll4(l0_flags, tid, (u32)(i + 1));
      __syncthreads();
    }

    const ushort_t* A1 = isL1 ? (h0ring + (size_t)(i & (RING_D - 1)) * BH)
                              : (ench1 + (size_t)i * BH);
    const ushort_t* A2 = isL1 ? (h1ring + (size_t)((i - 1) & (RING_D - 1)) * BH)
                              : (h0ring + (size_t)((i - 1) & (RING_D - 1)) * BH);
    const ushort_t* A = g ? A2 : A1;
    const ushort_t* Arow0 = A + (size_t)(mp * 32 + col) * HDIM + kh * 512 + kgrp * 8;
    const ushort_t* Arow1 = Arow0 + 16 * HDIM;

    // ---- A1 prefetch (g=0 waves): overlaps with own-group poll ----
    uint4 areg[32];
    if (g == 0) {
#pragma unroll
      for (int ko = 0; ko < 16; ++ko) {
        areg[2 * ko]     = ld_g128(Arow0 + ko * 32);
        areg[2 * ko + 1] = ld_g128(Arow1 + ko * 32);
      }
    }

    // ---- P2: own-group barrier (h(i-1) ready) + L0 ring guard ----
    if (tid < 32) {
      poll4(ownf, tid, (u32)i);
      if (!isL1 && i >= RING_D) poll4(l1_flags, tid, (u32)(i - RING_D + 1));
    }
    __syncthreads();

    // ---- A2 loads (g=1 waves) ----
    if (g == 1) {
#pragma unroll
      for (int ko = 0; ko < 16; ++ko) {
        areg[2 * ko]     = ld_g128(Arow0 + ko * 32);
        areg[2 * ko + 1] = ld_g128(Arow1 + ko * 32);
      }
    }

    // ---- MFMA, staged waits ----
    f32x4 acc00 = {0,0,0,0}, acc01 = {0,0,0,0}, acc10 = {0,0,0,0}, acc11 = {0,0,0,0};
    asm volatile("s_waitcnt vmcnt(16)" ::: "memory");
    __builtin_amdgcn_sched_barrier(0);
#pragma unroll
    for (int ko = 0; ko < 8; ++ko) {
      const short8 b0 = *(const short8*)(w0 + ko * 1024);
      const short8 b1 = *(const short8*)(w1 + ko * 512);
      U4S8 a0, a1; a0.u = areg[2 * ko]; a1.u = areg[2 * ko + 1];
      acc00 = __builtin_amdgcn_mfma_f32_16x16x32_bf16(a0.s, b0, acc00, 0, 0, 0);
      acc01 = __builtin_amdgcn_mfma_f32_16x16x32_bf16(a0.s, b1, acc01, 0, 0, 0);
      acc10 = __builtin_amdgcn_mfma_f32_16x16x32_bf16(a1.s, b0, acc10, 0, 0, 0);
      acc11 = __builtin_amdgcn_mfma_f32_16x16x32_bf16(a1.s, b1, acc11, 0, 0, 0);
    }
    asm volatile("s_waitcnt vmcnt(0)" ::: "memory");
    __builtin_amdgcn_sched_barrier(0);
#pragma unroll
    for (int ko = 8; ko < 16; ++ko) {
      const short8 b0 = *(const short8*)(w0 + ko * 1024);
      const short8 b1 = *(const short8*)(w1 + ko * 512);
      U4S8 a0, a1; a0.u = areg[2 * ko]; a1.u = areg[2 * ko + 1];
      acc00 = __builtin_amdgcn_mfma_f32_16x16x32_bf16(a0.s, b0, acc00, 0, 0, 0);
      acc01 = __builtin_amdgcn_mfma_f32_16x16x32_bf16(a0.s, b1, acc01, 0, 0, 0);
      acc10 = __builtin_amdgcn_mfma_f32_16x16x32_bf16(a1.s, b0, acc10, 0, 0, 0);
      acc11 = __builtin_amdgcn_mfma_f32_16x16x32_bf16(a1.s, b1, acc11, 0, 0, 0);
    }

    const int base = (wid * 4) * 256 + lane * 4;
    *(f32x4*)&lds_part[base      ] = acc00;
    *(f32x4*)&lds_part[base + 256] = acc01;
    *(f32x4*)&lds_part[base + 512] = acc10;
    *(f32x4*)&lds_part[base + 768] = acc11;

    __syncthreads();

    if (wid < 4) {
      const int m = wid, mpe = m >> 1, ime = m & 1;
      const int i00 = ((0 * 4 + 0 * 2 + mpe) * 4 + ime * 2);
      const int i01 = ((1 * 4 + 0 * 2 + mpe) * 4 + ime * 2);
      const int i10 = ((0 * 4 + 1 * 2 + mpe) * 4 + ime * 2);
      const int i11 = ((1 * 4 + 1 * 2 + mpe) * 4 + ime * 2);
      const int lo = lane * 4;
      f32x4 girz = *(f32x4*)&lds_part[i00 * 256 + lo] + *(f32x4*)&lds_part[i01 * 256 + lo];
      f32x4 gin  = *(f32x4*)&lds_part[(i00 + 1) * 256 + lo] + *(f32x4*)&lds_part[(i01 + 1) * 256 + lo];
      f32x4 ghrz = *(f32x4*)&lds_part[i10 * 256 + lo] + *(f32x4*)&lds_part[i11 * 256 + lo];
      f32x4 ghn  = *(f32x4*)&lds_part[(i10 + 1) * 256 + lo] + *(f32x4*)&lds_part[(i11 + 1) * 256 + lo];

      ushort_t* hdst = isL1 ? (h1ring + (size_t)(i & (RING_D - 1)) * BH)
                            : (h0ring + (size_t)(i & (RING_D - 1)) * BH);
      ushort_t* hall = isL1 ? (h1_all + (size_t)i * BH) : (ushort_t*)0;

#pragma unroll
      for (int e = 0; e < 4; ++e) {
        const float rz = sigm(girz[e] + ghrz[e] + bA);
        const float nv = tanhf(gin[e] + bB + rz * (ghn[e] + bC));
        const float zv = __shfl_xor(rz, 8);
        const int b = m * 16 + kgrp * 4 + e;
        float h = 0.f;
        if (col < 8) {
          h = (1.f - zv) * nv + zv * hp[e];
          hp[e] = h;
        }
        const u32 hb = f2bf_u(h);
        const u32 pb = (u32)__shfl_xor((int)hb, 1);
        if (col < 8 && (col & 1) == 0) {
          const u32 pack = hb | (pb << 16);
          st_sc32((u32*)(hdst + b * HDIM + j0 + col), pack);
          if (hall) st_sc32((u32*)(hall + b * HDIM + j0 + col), pack);
        }
      }
    }

    __syncthreads();  // all waves' stores drained (per-wave vmcnt 0 at barrier)
    if (tid == 0) st_sc32(ownf + gbid, (u32)(i + 1));
  }
}

// ---------- fused decoder + heads (bf16 MFMA) ----------
#define AST 1032
__global__ __launch_bounds__(512, 1) void dechead_kernel(
    const ushort_t* __restrict__ h1_all,
    const ushort_t* __restrict__ dwfrag, const ushort_t* __restrict__ hwfrag,
    const float* __restrict__ dec_b, const float* __restrict__ exp_b,
    const float* __restrict__ log_b, float* __restrict__ out)
{
  extern __shared__ char smem2[];
  ushort_t* Alds = (ushort_t*)smem2;             // [32][AST]
  ushort_t* Rlds = Alds + 32 * AST;              // [32][AST]

  const int tid  = threadIdx.x;
  const int lane = tid & 63;
  const int wv   = tid >> 6;
  const int base = blockIdx.x * 32;

  {
    const uint4* src = (const uint4*)(h1_all + (size_t)base * HDIM);
#pragma unroll
    for (int ii = 0; ii < 8; ++ii) {
      const int idx = ii * 512 + tid;
      const int row = idx >> 7;
      const int k   = (idx & 127) * 8;
      *(uint4*)(Alds + row * AST + k) = src[idx];
    }
  }
  __syncthreads();

  f32x4 acc[8][2];
#pragma unroll
  for (int t = 0; t < 8; ++t) { acc[t][0] = (f32x4){0,0,0,0}; acc[t][1] = (f32x4){0,0,0,0}; }

  const int r0 = lane & 15, kg = lane >> 4;
  const int nt0 = wv * 8;
#pragma unroll 1
  for (int t = 0; t < 8; ++t) {
    const ushort_t* bsrc = dwfrag + (size_t)(nt0 + t) * 32 * 512 + lane * 8;
    f32x4 c0 = acc[t][0], c1 = acc[t][1];
#pragma unroll
    for (int kc = 0; kc < 32; ++kc) {
      const short8 b  = *(const short8*)(bsrc + kc * 512);
      const short8 a0 = *(const short8*)(Alds + r0 * AST + kc * 32 + kg * 8);
      const short8 a1 = *(const short8*)(Alds + (16 + r0) * AST + kc * 32 + kg * 8);
      c0 = __builtin_amdgcn_mfma_f32_16x16x32_bf16(a0, b, c0, 0, 0, 0);
      c1 = __builtin_amdgcn_mfma_f32_16x16x32_bf16(a1, b, c1, 0, 0, 0);
    }
    acc[t][0] = c0; acc[t][1] = c1;
  }

#pragma unroll
  for (int t = 0; t < 8; ++t) {
    const int colc = (nt0 + t) * 16 + r0;
    const float db = dec_b[colc];
#pragma unroll
    for (int m = 0; m < 2; ++m) {
      const f32x4 v = acc[t][m];
#pragma unroll
      for (int e = 0; e < 4; ++e) {
        const int row = m * 16 + kg * 4 + e;
        Rlds[row * AST + colc] = (ushort_t)f2bf_u(tanhf(v[e] + db));
      }
    }
  }
  __syncthreads();

  f32x4 h0a = {0,0,0,0}, h1a = {0,0,0,0};
  {
    const ushort_t* bsrc = hwfrag + (size_t)wv * 32 * 512 + lane * 8;
#pragma unroll
    for (int kc = 0; kc < 32; ++kc) {
      const short8 b  = *(const short8*)(bsrc + kc * 512);
      const short8 a0 = *(const short8*)(Rlds + r0 * AST + kc * 32 + kg * 8);
      const short8 a1 = *(const short8*)(Rlds + (16 + r0) * AST + kc * 32 + kg * 8);
      h0a = __builtin_amdgcn_mfma_f32_16x16x32_bf16(a0, b, h0a, 0, 0, 0);
      h1a = __builtin_amdgcn_mfma_f32_16x16x32_bf16(a1, b, h1a, 0, 0, 0);
    }
  }
  const int y = wv * 16 + r0;
  if (wv < 4) {
    const float eb = exp_b[y];
#pragma unroll
    for (int m = 0; m < 2; ++m) {
      const f32x4 v = (m == 0) ? h0a : h1a;
#pragma unroll
      for (int e = 0; e < 4; ++e) {
        const int row = m * 16 + kg * 4 + e;
        out[(size_t)(base + row) * YDIM + y] = v[e] + eb;
      }
    }
  } else {
    const int yv = y - 64;
    const float lb = log_b[yv];
#pragma unroll
    for (int m = 0; m < 2; ++m) {
      const f32x4 v = (m == 0) ? h0a : h1a;
#pragma unroll
      for (int e = 0; e < 4; ++e) {
        const int row = m * 16 + kg * 4 + e;
        out[(size_t)(T_STEPS * BATCH * YDIM) + (size_t)(base + row) * YDIM + yv] = expf(v[e] + lb);
      }
    }
  }
}

// ---------- host ----------
extern "C" void kernel_launch(void* const* d_in, const int* in_sizes, int n_in,
                              void* d_out, int out_size, void* d_ws, size_t ws_size,
                              hipStream_t stream) {
  (void)in_sizes; (void)n_in; (void)out_size; (void)ws_size;
  const float* x     = (const float*)d_in[0];
  const float* enc_w = (const float*)d_in[1];
  const float* enc_b = (const float*)d_in[2];
  const float* w_ih  = (const float*)d_in[3];
  const float* w_hh  = (const float*)d_in[4];
  const float* b_ih  = (const float*)d_in[5];
  const float* b_hh  = (const float*)d_in[6];
  const float* dec_w = (const float*)d_in[7];
  const float* dec_b = (const float*)d_in[8];
  const float* exp_w = (const float*)d_in[9];
  const float* exp_b = (const float*)d_in[10];
  const float* log_w = (const float*)d_in[11];
  const float* log_b = (const float*)d_in[12];
  float* out = (float*)d_out;

  char* ws = (char*)d_ws;
  u32*      l0f     = (u32*)ws;                             // 128 u32 (contiguous)
  u32*      l1f     = (u32*)(ws + 4096);                    // 128 u32
  ushort_t* wfrag   = (ushort_t*)(ws + 2097152);            // 24 MB
  ushort_t* h0ring  = (ushort_t*)(ws + 27262976);           // 4 MB (32 slots)
  ushort_t* h1ring  = (ushort_t*)(ws + 31457280);           // 4 MB
  ushort_t* ench1   = (ushort_t*)(ws + 35651584);           // 64 MB enc slices / h1_all
  ushort_t* dwfrag  = (ushort_t*)(ws + 102760448);          // 2 MB
  ushort_t* hwfrag  = (ushort_t*)(ws + 104857600);          // 256 KB

  hipMemsetAsync(ws, 0, 8192, stream);                      // flag arrays
  hipMemsetAsync(ws + 27262976, 0, 8388608, stream);        // both rings

  enc_kernel<<<32768, 256, 0, stream>>>(x, enc_w, enc_b, ench1);
  wprep_kernel<<<8192, 256, 0, stream>>>(w_ih, w_hh, wfrag);
  wprep2_kernel<<<576, 256, 0, stream>>>(dec_w, exp_w, log_w, dwfrag, hwfrag);

  {
    static int lds_opted = 0;
    if (!lds_opted) {
      (void)hipFuncSetAttribute((const void*)rnn_persist,
                          hipFuncAttributeMaxDynamicSharedMemorySize, 131072);
      (void)hipFuncSetAttribute((const void*)dechead_kernel,
                          hipFuncAttributeMaxDynamicSharedMemorySize, 2 * 32 * AST * 2);
      lds_opted = 1;
    }
    void* args[9];
    args[0] = (void*)&ench1;
    args[1] = (void*)&wfrag;
    args[2] = (void*)&b_ih;
    args[3] = (void*)&b_hh;
    args[4] = (void*)&h0ring;
    args[5] = (void*)&h1ring;
    args[6] = (void*)&ench1;
    args[7] = (void*)&l0f;
    args[8] = (void*)&l1f;
    (void)hipLaunchCooperativeKernel((const void*)rnn_persist, dim3(256), dim3(512),
                               args, 131072, stream);
  }

  dechead_kernel<<<1024, 512, 2 * 32 * AST * 2, stream>>>(
      ench1, dwfrag, hwfrag, dec_b, exp_b, log_b, out);
}